// Round 5
// baseline (121.438 us; speedup 1.0000x reference)
//
#include <hip/hip_runtime.h>
#include <hip/hip_fp16.h>
#include <math.h>

#define B_  8
#define H_  64
#define W_  64
#define C_  128
#define F_  256
#define NOC 27

typedef float    f32x4 __attribute__((ext_vector_type(4)));
typedef _Float16 f16x8 __attribute__((ext_vector_type(8)));

// ws layout (float units):
//   woffT : f16[9][32][128]   @ 0        (73728 B)
//   filtT : f16[9][256][128]  @ 32768    (589824 B)
//   wi32  : float[32768][32]  @ 180224   (4 MB)
#define FILTT_OFF_F 32768
#define WI32_OFF_F  180224

static __device__ __forceinline__ unsigned pkh2(float a, float b) {
    __half2 h = __floats2half2_rn(a, b);
    union { __half2 h2; unsigned u; } cv; cv.h2 = h;
    return cv.u;
}

// ---------------------------------------------------------------- repack (f32 -> f16)
__global__ __launch_bounds__(256) void repack(const float* __restrict__ kofs,
                                              const float* __restrict__ filt,
                                              unsigned short* __restrict__ woffT,
                                              unsigned short* __restrict__ filtT) {
    int idx = blockIdx.x * 256 + threadIdx.x;
    if (idx < 9 * 32 * 128) {
        int tap = idx >> 12;
        int r   = idx & 4095;
        int oc  = r >> 7;
        int c   = r & 127;
        float v = (oc < NOC) ? kofs[(tap * C_ + c) * NOC + oc] : 0.f;
        union { __half h; unsigned short u; } cv; cv.h = __float2half(v);
        woffT[idx] = cv.u;
        return;
    }
    int idx2 = idx - 9 * 32 * 128;
    if (idx2 < 9 * 256 * 128) {
        int tap = idx2 / 32768;
        int r   = idx2 & 32767;
        int f   = r >> 7;
        int c   = r & 127;
        float v = filt[(tap * C_ + c) * F_ + f];
        union { __half h; unsigned short u; } cv; cv.h = __float2half(v);
        filtT[idx2] = cv.u;
    }
}

// ---------------------------------------------------------------- offset conv (f16 MFMA)
// block = one image row (64 px), 256 thr / 4 waves. XCD x <-> image x.
__global__ __launch_bounds__(256) void offset_conv_mfma(const float* __restrict__ in,
                                                        const unsigned short* __restrict__ woffT,
                                                        const float* __restrict__ bias,
                                                        float* __restrict__ wi32) {
    __shared__ __align__(16) unsigned char win[3 * 66 * 256];   // 50688 B

    int t    = threadIdx.x;
    int bid  = blockIdx.x;
    int lg   = ((bid & 7) << 6) | (bid >> 3);       // 512 = 8*64
    int bb   = lg >> 6;
    int hh   = lg & 63;
    int pix0 = lg << 6;

    for (int idx = t; idx < 3 * 66 * 32; idx += 256) {
        int ky = idx / (66 * 32);
        int r  = idx % (66 * 32);
        int xi = r >> 5;
        int c4 = r & 31;
        int y  = hh + ky - 1;
        int x  = xi - 1;
        uint2 v = make_uint2(0u, 0u);
        if ((unsigned)y < 64u && (unsigned)x < 64u) {
            float4 f = *(const float4*)((const char*)in +
                    ((size_t)(((bb << 6) + y) * 64 + x) << 9) + (c4 << 4));
            v = make_uint2(pkh2(f.x, f.y), pkh2(f.z, f.w));
        }
        *(uint2*)(win + ky * 16896 + xi * 256 + ((c4 << 3) ^ ((xi & 7) << 4))) = v;
    }
    __syncthreads();

    int lane = t & 63, wv = t >> 6;
    int row  = lane & 15, kg = lane >> 4;
    int px0  = wv << 4;

    f32x4 z = {0.f, 0.f, 0.f, 0.f};
    f32x4 acc[2] = {z, z};

    for (int tap = 0; tap < 9; ++tap) {
        int ky = tap / 3, kx = tap - ky * 3;
        int xi = px0 + row + kx;
        const unsigned char* arow = win + ky * 16896 + xi * 256;
        int sw = (xi & 7) << 4;
        const unsigned short* bp = woffT + (size_t)tap * 4096 + (size_t)row * 128 + kg * 8;
        #pragma unroll
        for (int ks = 0; ks < 4; ++ks) {
            f16x8 a  = *(const f16x8*)(arow + ((ks * 64 + kg * 16) ^ sw));
            f16x8 b0 = *(const f16x8*)(bp + ks * 32);
            f16x8 b1 = *(const f16x8*)(bp + 2048 + ks * 32);
            acc[0] = __builtin_amdgcn_mfma_f32_16x16x32_f16(a, b0, acc[0], 0, 0, 0);
            acc[1] = __builtin_amdgcn_mfma_f32_16x16x32_f16(a, b1, acc[1], 0, 0, 0);
        }
    }

    #pragma unroll
    for (int n = 0; n < 2; ++n) {
        int oc = n * 16 + row;
        float bv = (oc < NOC) ? bias[oc] : 0.f;
        #pragma unroll
        for (int r = 0; r < 4; ++r) {
            int px = px0 + kg * 4 + r;
            wi32[(size_t)(pix0 + px) * 32 + oc] = acc[n][r] + bv;
        }
    }
}

// ---------------------------------------------------------------- main deform conv
// block = 2 image rows (128 px) x 256 F, 1024 thr / 16 waves, 1 block/CU.
// 6-row f16 LDS window; bilinear sampling from LDS (pk_fma_f16); rare
// out-of-window offsets fall back to global gather. XCD x <-> image x.
__global__ __launch_bounds__(1024) void deform_mfma(const float* __restrict__ in,
                                                    const unsigned short* __restrict__ filtT,
                                                    const float* __restrict__ wi32,
                                                    float* __restrict__ out) {
    __shared__ __align__(16) unsigned char win[6 * 64 * 256];   // 98304 B
    __shared__ __align__(16) unsigned char At[128 * 256];       // 32768 B
    __shared__ __align__(16) uint4 prm[128 * 9];                // 18432 B

    int t    = threadIdx.x;
    int bid  = blockIdx.x;
    int lg   = ((bid & 7) << 5) | (bid >> 3);       // 256 = 8*32, XCD-bijective
    int bb   = lg >> 5;
    int rem  = lg & 31;
    int hh0  = rem << 1;
    int pix0 = lg << 7;

    const char* ib = (const char*)in;

    // ---- per-(px,tap) sampling params (1152 items)
    for (int it = t; it < 1152; it += 1024) {
        int tap = it >> 7;
        int px  = it & 127;
        int hh  = hh0 + (px >> 6);
        int col = px & 63;
        const float* wp = wi32 + (size_t)(pix0 + px) * 32;
        float o1 = wp[tap], o2 = wp[9 + tap], mm = wp[18 + tap];
        float mask = 1.f / (1.f + __expf(-mm));
        int ky = tap / 3, kx = tap - ky * 3;
        float py  = (float)(hh - 1 + ky) + o1;
        float pxx = (float)(col - 1 + kx) + o2;
        float y0f = floorf(py), x0f = floorf(pxx);
        float wy1 = py - y0f,  wy0 = 1.f - wy1;
        float wx1 = pxx - x0f, wx0 = 1.f - wx1;
        float vy0 = (y0f >=  0.f && y0f <= 63.f) ? 1.f : 0.f;
        float vy1 = (y0f >= -1.f && y0f <= 62.f) ? 1.f : 0.f;
        float vx0 = (x0f >=  0.f && x0f <= 63.f) ? 1.f : 0.f;
        float vx1 = (x0f >= -1.f && x0f <= 62.f) ? 1.f : 0.f;
        int y0 = (int)fminf(fmaxf(y0f,       0.f), 63.f);
        int y1 = (int)fminf(fmaxf(y0f + 1.f, 0.f), 63.f);
        int x0 = (int)fminf(fmaxf(x0f,       0.f), 63.f);
        int x1 = (int)fminf(fmaxf(x0f + 1.f, 0.f), 63.f);
        uint4 P;
        if (y0 >= hh0 - 2 && y1 <= hh0 + 3) {       // clamped corners inside window
            unsigned wy0i = (unsigned)(y0 - (hh0 - 2));
            unsigned wy1i = (unsigned)(y1 - (hh0 - 2));
            P.x = (wy0i * 64 + x0) | ((wy0i * 64 + x1) << 16);
            P.y = (wy1i * 64 + x0) | ((wy1i * 64 + x1) << 16);
        } else {
            P.x = 0xFFFFu; P.y = 0u;                // slow-path sentinel
        }
        P.z = pkh2(wy0 * wx0 * mask * vy0 * vx0, wy0 * wx1 * mask * vy0 * vx1);
        P.w = pkh2(wy1 * wx0 * mask * vy1 * vx0, wy1 * wx1 * mask * vy1 * vx1);
        prm[px * 9 + tap] = P;
    }

    // ---- stage 6-row f16 window (rows hh0-2 .. hh0+3)
    for (int it = t; it < 6 * 64 * 32; it += 1024) {
        int wy = it >> 11;
        int r  = it & 2047;
        int wx = r >> 5;
        int c4 = r & 31;
        int y  = hh0 - 2 + wy;
        uint2 v = make_uint2(0u, 0u);
        if ((unsigned)y < 64u) {
            float4 f = *(const float4*)(ib +
                    ((size_t)(((bb << 6) + y) * 64 + wx) << 9) + (c4 << 4));
            v = make_uint2(pkh2(f.x, f.y), pkh2(f.z, f.w));
        }
        *(uint2*)(win + wy * 16384 + wx * 256 + ((c4 << 3) ^ ((wx & 7) << 4))) = v;
    }
    __syncthreads();

    int lane = t & 63, wv = t >> 6;
    int row  = lane & 15, kg = lane >> 4;
    int wr   = wv >> 2, wc = wv & 3;
    int c4   = t & 31,  pg = t >> 5;     // sampling split: 32 ch-groups x 32 px-groups

    f32x4 z = {0.f, 0.f, 0.f, 0.f};
    f32x4 acc[2][4];
    #pragma unroll
    for (int m = 0; m < 2; ++m)
        #pragma unroll
        for (int n = 0; n < 4; ++n) acc[m][n] = z;

    for (int tap = 0; tap < 9; ++tap) {
        // ---- sample phase: 4 px per thread, 4 ch each, from LDS window
        #pragma unroll
        for (int pp = 0; pp < 4; ++pp) {
            int px = pg + (pp << 5);
            uint4 P = prm[px * 9 + tap];
            uint2 sv;
            if ((P.x & 0xFFFFu) != 0xFFFFu) {
                unsigned o00 = P.x & 0xFFFFu, o01 = P.x >> 16;
                unsigned o10 = P.y & 0xFFFFu, o11 = P.y >> 16;
                int cb = c4 << 3;
                union { uint2 u; __half2 h[2]; } r00, r01, r10, r11;
                r00.u = *(const uint2*)(win + (o00 << 8) + (cb ^ ((o00 & 7) << 4)));
                r01.u = *(const uint2*)(win + (o01 << 8) + (cb ^ ((o01 & 7) << 4)));
                r10.u = *(const uint2*)(win + (o10 << 8) + (cb ^ ((o10 & 7) << 4)));
                r11.u = *(const uint2*)(win + (o11 << 8) + (cb ^ ((o11 & 7) << 4)));
                union { unsigned u; __half2 h; } w00, w01, w10, w11;
                w00.u = (P.z & 0xFFFFu) * 0x10001u;
                w01.u = (P.z >> 16)     * 0x10001u;
                w10.u = (P.w & 0xFFFFu) * 0x10001u;
                w11.u = (P.w >> 16)     * 0x10001u;
                __half2 s0 = __hmul2(r00.h[0], w00.h);
                s0 = __hfma2(r01.h[0], w01.h, s0);
                s0 = __hfma2(r10.h[0], w10.h, s0);
                s0 = __hfma2(r11.h[0], w11.h, s0);
                __half2 s1 = __hmul2(r00.h[1], w00.h);
                s1 = __hfma2(r01.h[1], w01.h, s1);
                s1 = __hfma2(r10.h[1], w10.h, s1);
                s1 = __hfma2(r11.h[1], w11.h, s1);
                union { __half2 h; unsigned u; } c0, c1; c0.h = s0; c1.h = s1;
                sv = make_uint2(c0.u, c1.u);
            } else {
                // slow path: recompute + global gather (rare)
                int hh  = hh0 + (px >> 6);
                int col = px & 63;
                const float* wp = wi32 + (size_t)(pix0 + px) * 32;
                float o1 = wp[tap], o2 = wp[9 + tap], mm = wp[18 + tap];
                float mask = 1.f / (1.f + __expf(-mm));
                int ky = tap / 3, kx = tap - ky * 3;
                float py  = (float)(hh - 1 + ky) + o1;
                float pxx = (float)(col - 1 + kx) + o2;
                float y0f = floorf(py), x0f = floorf(pxx);
                float wy1 = py - y0f,  wy0 = 1.f - wy1;
                float wx1 = pxx - x0f, wx0 = 1.f - wx1;
                float vy0 = (y0f >=  0.f && y0f <= 63.f) ? 1.f : 0.f;
                float vy1 = (y0f >= -1.f && y0f <= 62.f) ? 1.f : 0.f;
                float vx0 = (x0f >=  0.f && x0f <= 63.f) ? 1.f : 0.f;
                float vx1 = (x0f >= -1.f && x0f <= 62.f) ? 1.f : 0.f;
                int y0 = (int)fminf(fmaxf(y0f,       0.f), 63.f);
                int y1 = (int)fminf(fmaxf(y0f + 1.f, 0.f), 63.f);
                int x0 = (int)fminf(fmaxf(x0f,       0.f), 63.f);
                int x1 = (int)fminf(fmaxf(x0f + 1.f, 0.f), 63.f);
                float w00 = wy0 * wx0 * mask * vy0 * vx0;
                float w01 = wy0 * wx1 * mask * vy0 * vx1;
                float w10 = wy1 * wx0 * mask * vy1 * vx0;
                float w11 = wy1 * wx1 * mask * vy1 * vx1;
                size_t base = (size_t)bb << 21;
                int cb16 = c4 << 4;
                float4 v00 = *(const float4*)(ib + base + ((size_t)((y0 << 6) + x0) << 9) + cb16);
                float4 v01 = *(const float4*)(ib + base + ((size_t)((y0 << 6) + x1) << 9) + cb16);
                float4 v10 = *(const float4*)(ib + base + ((size_t)((y1 << 6) + x0) << 9) + cb16);
                float4 v11 = *(const float4*)(ib + base + ((size_t)((y1 << 6) + x1) << 9) + cb16);
                float sx = w00 * v00.x + w01 * v01.x + w10 * v10.x + w11 * v11.x;
                float sy = w00 * v00.y + w01 * v01.y + w10 * v10.y + w11 * v11.y;
                float sz = w00 * v00.z + w01 * v01.z + w10 * v10.z + w11 * v11.z;
                float sw = w00 * v00.w + w01 * v01.w + w10 * v10.w + w11 * v11.w;
                sv = make_uint2(pkh2(sx, sy), pkh2(sz, sw));
            }
            *(uint2*)(At + (px << 8) + ((c4 << 3) ^ ((px & 7) << 4))) = sv;
        }
        __syncthreads();
        // ---- MFMA phase: wave tile 32 px x 64 F
        const unsigned short* bp = filtT + (size_t)tap * 32768 +
                                   (size_t)(wc * 64 + row) * 128 + kg * 8;
        #pragma unroll
        for (int ks = 0; ks < 4; ++ks) {
            f16x8 a[2], bf[4];
            #pragma unroll
            for (int m = 0; m < 2; ++m)
                a[m] = *(const f16x8*)(At + ((wr * 32 + m * 16 + row) << 8) +
                            ((ks * 64 + kg * 16) ^ ((row & 7) << 4)));
            #pragma unroll
            for (int n = 0; n < 4; ++n)
                bf[n] = *(const f16x8*)(bp + n * 2048 + ks * 32);
            #pragma unroll
            for (int m = 0; m < 2; ++m)
                #pragma unroll
                for (int n = 0; n < 4; ++n)
                    acc[m][n] = __builtin_amdgcn_mfma_f32_16x16x32_f16(a[m], bf[n], acc[m][n], 0, 0, 0);
        }
        __syncthreads();
    }

    // ---- epilogue
    #pragma unroll
    for (int m = 0; m < 2; ++m)
        #pragma unroll
        for (int r = 0; r < 4; ++r) {
            int px = wr * 32 + m * 16 + kg * 4 + r;
            float* op = out + (size_t)(pix0 + px) * 256 + wc * 64 + row;
            op[0]  = acc[m][0][r];
            op[16] = acc[m][1][r];
            op[32] = acc[m][2][r];
            op[48] = acc[m][3][r];
        }
}

// ---------------------------------------------------------------- launch
extern "C" void kernel_launch(void* const* d_in, const int* in_sizes, int n_in,
                              void* d_out, int out_size, void* d_ws, size_t ws_size,
                              hipStream_t stream) {
    const float* in   = (const float*)d_in[0];
    const float* kofs = (const float*)d_in[1];
    const float* bias = (const float*)d_in[2];
    const float* filt = (const float*)d_in[3];
    float* out = (float*)d_out;
    float* ws  = (float*)d_ws;

    unsigned short* woffT = (unsigned short*)ws;
    unsigned short* filtT = (unsigned short*)(ws + FILTT_OFF_F);
    float*          wi32  = ws + WI32_OFF_F;

    hipLaunchKernelGGL(repack, dim3(1296), dim3(256), 0, stream, kofs, filt, woffT, filtT);
    hipLaunchKernelGGL(offset_conv_mfma, dim3(512), dim3(256), 0, stream, in, woffT, bias, wi32);
    hipLaunchKernelGGL(deform_mfma, dim3(256), dim3(1024), 0, stream, in, filtT, wi32, out);
}

// Round 6
// 112.083 us; speedup vs baseline: 1.0835x; 1.0835x over previous
//
#include <hip/hip_runtime.h>
#include <hip/hip_fp16.h>
#include <math.h>

#define B_  8
#define H_  64
#define W_  64
#define C_  128
#define F_  256
#define NOC 27

typedef float    f32x4 __attribute__((ext_vector_type(4)));
typedef _Float16 f16x8 __attribute__((ext_vector_type(8)));

// ws layout (float units):
//   woffT : f16[9][32][128]   @ 0        (73728 B)
//   filtT : f16[9][256][128]  @ 32768    (589824 B)
//   wi32  : float[32768][32]  @ 180224   (4 MB)
#define FILTT_OFF_F 32768
#define WI32_OFF_F  180224

static __device__ __forceinline__ unsigned pkh2(float a, float b) {
    __half2 h = __floats2half2_rn(a, b);
    union { __half2 h2; unsigned u; } cv; cv.h2 = h;
    return cv.u;
}

// ---------------------------------------------------------------- repack (f32 -> f16)
__global__ __launch_bounds__(256) void repack(const float* __restrict__ kofs,
                                              const float* __restrict__ filt,
                                              unsigned short* __restrict__ woffT,
                                              unsigned short* __restrict__ filtT) {
    int idx = blockIdx.x * 256 + threadIdx.x;
    if (idx < 9 * 32 * 128) {
        int tap = idx >> 12;
        int r   = idx & 4095;
        int oc  = r >> 7;
        int c   = r & 127;
        float v = (oc < NOC) ? kofs[(tap * C_ + c) * NOC + oc] : 0.f;
        union { __half h; unsigned short u; } cv; cv.h = __float2half(v);
        woffT[idx] = cv.u;
        return;
    }
    int idx2 = idx - 9 * 32 * 128;
    if (idx2 < 9 * 256 * 128) {
        int tap = idx2 / 32768;
        int r   = idx2 & 32767;
        int f   = r >> 7;
        int c   = r & 127;
        float v = filt[(tap * C_ + c) * F_ + f];
        union { __half h; unsigned short u; } cv; cv.h = __float2half(v);
        filtT[idx2] = cv.u;
    }
}

// ---------------------------------------------------------------- offset conv (f16 MFMA)
__global__ __launch_bounds__(256) void offset_conv_mfma(const float* __restrict__ in,
                                                        const unsigned short* __restrict__ woffT,
                                                        const float* __restrict__ bias,
                                                        float* __restrict__ wi32) {
    __shared__ __align__(16) unsigned char win[3 * 66 * 256];   // 50688 B

    int t    = threadIdx.x;
    int bid  = blockIdx.x;
    int lg   = ((bid & 7) << 6) | (bid >> 3);       // 512 = 8*64
    int bb   = lg >> 6;
    int hh   = lg & 63;
    int pix0 = lg << 6;

    for (int idx = t; idx < 3 * 66 * 32; idx += 256) {
        int ky = idx / (66 * 32);
        int r  = idx % (66 * 32);
        int xi = r >> 5;
        int c4 = r & 31;
        int y  = hh + ky - 1;
        int x  = xi - 1;
        uint2 v = make_uint2(0u, 0u);
        if ((unsigned)y < 64u && (unsigned)x < 64u) {
            float4 f = *(const float4*)((const char*)in +
                    ((size_t)(((bb << 6) + y) * 64 + x) << 9) + (c4 << 4));
            v = make_uint2(pkh2(f.x, f.y), pkh2(f.z, f.w));
        }
        *(uint2*)(win + ky * 16896 + xi * 256 + ((c4 << 3) ^ ((xi & 7) << 4))) = v;
    }
    __syncthreads();

    int lane = t & 63, wv = t >> 6;
    int row  = lane & 15, kg = lane >> 4;
    int px0  = wv << 4;

    f32x4 z = {0.f, 0.f, 0.f, 0.f};
    f32x4 acc[2] = {z, z};

    for (int tap = 0; tap < 9; ++tap) {
        int ky = tap / 3, kx = tap - ky * 3;
        int xi = px0 + row + kx;
        const unsigned char* arow = win + ky * 16896 + xi * 256;
        int sw = (xi & 7) << 4;
        const unsigned short* bp = woffT + (size_t)tap * 4096 + (size_t)row * 128 + kg * 8;
        #pragma unroll
        for (int ks = 0; ks < 4; ++ks) {
            f16x8 a  = *(const f16x8*)(arow + ((ks * 64 + kg * 16) ^ sw));
            f16x8 b0 = *(const f16x8*)(bp + ks * 32);
            f16x8 b1 = *(const f16x8*)(bp + 2048 + ks * 32);
            acc[0] = __builtin_amdgcn_mfma_f32_16x16x32_f16(a, b0, acc[0], 0, 0, 0);
            acc[1] = __builtin_amdgcn_mfma_f32_16x16x32_f16(a, b1, acc[1], 0, 0, 0);
        }
    }

    #pragma unroll
    for (int n = 0; n < 2; ++n) {
        int oc = n * 16 + row;
        float bv = (oc < NOC) ? bias[oc] : 0.f;
        #pragma unroll
        for (int r = 0; r < 4; ++r) {
            int px = px0 + kg * 4 + r;
            wi32[(size_t)(pix0 + px) * 32 + oc] = acc[n][r] + bv;
        }
    }
}

// ---------------------------------------------------------------- main deform conv
// block = 2 image rows (128 px) x 256 F, 1024 thr / 16 waves (4wr x 4wc),
// wave tile 32 px x 64 F. ONE barrier total: after window+param staging.
// Each lane samples its own MFMA A-fragment from the LDS window into regs.
__global__ __launch_bounds__(1024) void deform_wave(const float* __restrict__ in,
                                                    const unsigned short* __restrict__ filtT,
                                                    const float* __restrict__ wi32,
                                                    float* __restrict__ out) {
    __shared__ __align__(16) unsigned char win[6 * 64 * 256];   // 98304 B
    __shared__ __align__(16) uint4 prm[128 * 9];                // 18432 B

    int t    = threadIdx.x;
    int bid  = blockIdx.x;
    int lg   = ((bid & 7) << 5) | (bid >> 3);       // 256 = 8*32, XCD-bijective
    int bb   = lg >> 5;
    int rem  = lg & 31;
    int hh0  = rem << 1;
    int pix0 = (bb << 12) + (hh0 << 6);

    const char* ib = (const char*)in;

    // ---- per-(px,tap) sampling params (1152 items)
    for (int it = t; it < 1152; it += 1024) {
        int tap = it >> 7;
        int px  = it & 127;
        int hh  = hh0 + (px >> 6);
        int col = px & 63;
        const float* wp = wi32 + (size_t)(pix0 + px) * 32;
        float o1 = wp[tap], o2 = wp[9 + tap], mm = wp[18 + tap];
        float mask = 1.f / (1.f + __expf(-mm));
        int ky = tap / 3, kx = tap - ky * 3;
        float py  = (float)(hh - 1 + ky) + o1;
        float pxx = (float)(col - 1 + kx) + o2;
        float y0f = floorf(py), x0f = floorf(pxx);
        float wy1 = py - y0f,  wy0 = 1.f - wy1;
        float wx1 = pxx - x0f, wx0 = 1.f - wx1;
        float vy0 = (y0f >=  0.f && y0f <= 63.f) ? 1.f : 0.f;
        float vy1 = (y0f >= -1.f && y0f <= 62.f) ? 1.f : 0.f;
        float vx0 = (x0f >=  0.f && x0f <= 63.f) ? 1.f : 0.f;
        float vx1 = (x0f >= -1.f && x0f <= 62.f) ? 1.f : 0.f;
        int y0 = (int)fminf(fmaxf(y0f,       0.f), 63.f);
        int y1 = (int)fminf(fmaxf(y0f + 1.f, 0.f), 63.f);
        int x0 = (int)fminf(fmaxf(x0f,       0.f), 63.f);
        int x1 = (int)fminf(fmaxf(x0f + 1.f, 0.f), 63.f);
        uint4 P;
        if (y0 >= hh0 - 2 && y1 <= hh0 + 3) {       // clamped corners inside window
            unsigned wy0i = (unsigned)(y0 - (hh0 - 2));
            unsigned wy1i = (unsigned)(y1 - (hh0 - 2));
            P.x = (wy0i * 64 + x0) | ((wy0i * 64 + x1) << 16);
            P.y = (wy1i * 64 + x0) | ((wy1i * 64 + x1) << 16);
        } else {
            P.x = 0xFFFFu; P.y = 0u;                // slow-path sentinel
        }
        P.z = pkh2(wy0 * wx0 * mask * vy0 * vx0, wy0 * wx1 * mask * vy0 * vx1);
        P.w = pkh2(wy1 * wx0 * mask * vy1 * vx0, wy1 * wx1 * mask * vy1 * vx1);
        prm[px * 9 + tap] = P;
    }

    // ---- stage 6-row f16 window (rows hh0-2 .. hh0+3)
    for (int it = t; it < 6 * 64 * 32; it += 1024) {
        int wy = it >> 11;
        int r  = it & 2047;
        int wx = r >> 5;
        int c4 = r & 31;
        int y  = hh0 - 2 + wy;
        uint2 v = make_uint2(0u, 0u);
        if ((unsigned)y < 64u) {
            float4 f = *(const float4*)(ib +
                    ((size_t)(((bb << 6) + y) * 64 + wx) << 9) + (c4 << 4));
            v = make_uint2(pkh2(f.x, f.y), pkh2(f.z, f.w));
        }
        *(uint2*)(win + wy * 16384 + wx * 256 + ((c4 << 3) ^ ((wx & 7) << 4))) = v;
    }
    __syncthreads();          // the only block-wide barrier

    int lane = t & 63, wv = t >> 6;
    int wr   = wv >> 2, wc = wv & 3;
    int arow = lane & 15;     // A-row / B f-col lane index
    int kq   = lane >> 4;     // channel sub-chunk (8 ch = 16B)

    const char* fbp = (const char*)filtT +
                      (size_t)(((wc << 6) + arow) * 128 + (kq << 3)) * 2;

    f32x4 z = {0.f, 0.f, 0.f, 0.f};
    f32x4 acc[2][4];
    #pragma unroll
    for (int m = 0; m < 2; ++m)
        #pragma unroll
        for (int n = 0; n < 4; ++n) acc[m][n] = z;

    #pragma unroll 1
    for (int tap = 0; tap < 9; ++tap) {
        union AU { uint4 u; __half2 h[4]; f16x8 v; };
        f16x8 a[2][4];
        #pragma unroll
        for (int m = 0; m < 2; ++m) {
            int px = (wr << 5) + (m << 4) + arow;
            uint4 P = prm[px * 9 + tap];
            if ((P.x & 0xFFFFu) != 0xFFFFu) {
                unsigned o00 = P.x & 0xFFFFu, o01 = P.x >> 16;
                unsigned o10 = P.y & 0xFFFFu, o11 = P.y >> 16;
                union { unsigned u; __half2 h; } w00, w01, w10, w11;
                w00.u = (P.z & 0xFFFFu) * 0x10001u;
                w01.u = (P.z >> 16)     * 0x10001u;
                w10.u = (P.w & 0xFFFFu) * 0x10001u;
                w11.u = (P.w >> 16)     * 0x10001u;
                #pragma unroll
                for (int ks = 0; ks < 4; ++ks) {
                    int cb = (ks << 6) + (kq << 4);
                    AU c00, c01, c10, c11, s;
                    c00.u = *(const uint4*)(win + (o00 << 8) + (cb ^ ((o00 & 7) << 4)));
                    c01.u = *(const uint4*)(win + (o01 << 8) + (cb ^ ((o01 & 7) << 4)));
                    c10.u = *(const uint4*)(win + (o10 << 8) + (cb ^ ((o10 & 7) << 4)));
                    c11.u = *(const uint4*)(win + (o11 << 8) + (cb ^ ((o11 & 7) << 4)));
                    #pragma unroll
                    for (int j = 0; j < 4; ++j) {
                        __half2 sj = __hmul2(c00.h[j], w00.h);
                        sj = __hfma2(c01.h[j], w01.h, sj);
                        sj = __hfma2(c10.h[j], w10.h, sj);
                        s.h[j] = __hfma2(c11.h[j], w11.h, sj);
                    }
                    a[m][ks] = s.v;
                }
            } else {
                // slow path: recompute + global f32 gather (rare, exec-masked)
                int hh  = hh0 + (px >> 6);
                int col = px & 63;
                const float* wp = wi32 + (size_t)(pix0 + px) * 32;
                float o1 = wp[tap], o2 = wp[9 + tap], mm = wp[18 + tap];
                float mask = 1.f / (1.f + __expf(-mm));
                int ky = tap / 3, kx = tap - ky * 3;
                float py  = (float)(hh - 1 + ky) + o1;
                float pxx = (float)(col - 1 + kx) + o2;
                float y0f = floorf(py), x0f = floorf(pxx);
                float wy1 = py - y0f,  wy0 = 1.f - wy1;
                float wx1 = pxx - x0f, wx0 = 1.f - wx1;
                float vy0 = (y0f >=  0.f && y0f <= 63.f) ? 1.f : 0.f;
                float vy1 = (y0f >= -1.f && y0f <= 62.f) ? 1.f : 0.f;
                float vx0 = (x0f >=  0.f && x0f <= 63.f) ? 1.f : 0.f;
                float vx1 = (x0f >= -1.f && x0f <= 62.f) ? 1.f : 0.f;
                int y0 = (int)fminf(fmaxf(y0f,       0.f), 63.f);
                int y1 = (int)fminf(fmaxf(y0f + 1.f, 0.f), 63.f);
                int x0 = (int)fminf(fmaxf(x0f,       0.f), 63.f);
                int x1 = (int)fminf(fmaxf(x0f + 1.f, 0.f), 63.f);
                float w00 = wy0 * wx0 * mask * vy0 * vx0;
                float w01 = wy0 * wx1 * mask * vy0 * vx1;
                float w10 = wy1 * wx0 * mask * vy1 * vx0;
                float w11 = wy1 * wx1 * mask * vy1 * vx1;
                size_t base = (size_t)bb << 21;
                size_t r00 = base + ((size_t)((y0 << 6) + x0) << 9);
                size_t r01 = base + ((size_t)((y0 << 6) + x1) << 9);
                size_t r10 = base + ((size_t)((y1 << 6) + x0) << 9);
                size_t r11 = base + ((size_t)((y1 << 6) + x1) << 9);
                #pragma unroll
                for (int ks = 0; ks < 4; ++ks) {
                    int cf = ((ks << 5) + (kq << 3)) << 2;
                    float4 pA = *(const float4*)(ib + r00 + cf);
                    float4 pB = *(const float4*)(ib + r00 + cf + 16);
                    float4 qA = *(const float4*)(ib + r01 + cf);
                    float4 qB = *(const float4*)(ib + r01 + cf + 16);
                    float4 sA = *(const float4*)(ib + r10 + cf);
                    float4 sB = *(const float4*)(ib + r10 + cf + 16);
                    float4 tA = *(const float4*)(ib + r11 + cf);
                    float4 tB = *(const float4*)(ib + r11 + cf + 16);
                    float e0 = w00 * pA.x + w01 * qA.x + w10 * sA.x + w11 * tA.x;
                    float e1 = w00 * pA.y + w01 * qA.y + w10 * sA.y + w11 * tA.y;
                    float e2 = w00 * pA.z + w01 * qA.z + w10 * sA.z + w11 * tA.z;
                    float e3 = w00 * pA.w + w01 * qA.w + w10 * sA.w + w11 * tA.w;
                    float e4 = w00 * pB.x + w01 * qB.x + w10 * sB.x + w11 * tB.x;
                    float e5 = w00 * pB.y + w01 * qB.y + w10 * sB.y + w11 * tB.y;
                    float e6 = w00 * pB.z + w01 * qB.z + w10 * sB.z + w11 * tB.z;
                    float e7 = w00 * pB.w + w01 * qB.w + w10 * sB.w + w11 * tB.w;
                    AU s;
                    s.u = make_uint4(pkh2(e0, e1), pkh2(e2, e3),
                                     pkh2(e4, e5), pkh2(e6, e7));
                    a[m][ks] = s.v;
                }
            }
        }
        // ---- B + MFMA (L2-hot B, no LDS, no barrier)
        const char* ft = fbp + (size_t)tap * 65536;
        __builtin_amdgcn_s_setprio(1);
        #pragma unroll
        for (int n = 0; n < 4; ++n) {
            #pragma unroll
            for (int ks = 0; ks < 4; ++ks) {
                f16x8 bv = *(const f16x8*)(ft + n * 4096 + (ks << 6));
                acc[0][n] = __builtin_amdgcn_mfma_f32_16x16x32_f16(a[0][ks], bv, acc[0][n], 0, 0, 0);
                acc[1][n] = __builtin_amdgcn_mfma_f32_16x16x32_f16(a[1][ks], bv, acc[1][n], 0, 0, 0);
            }
        }
        __builtin_amdgcn_s_setprio(0);
    }

    // ---- epilogue: D row px = 4*kq + reg, col f = arow
    #pragma unroll
    for (int m = 0; m < 2; ++m)
        #pragma unroll
        for (int r = 0; r < 4; ++r) {
            int px = (wr << 5) + (m << 4) + (kq << 2) + r;
            float* op = out + (size_t)(pix0 + px) * 256 + (wc << 6) + arow;
            op[0]  = acc[m][0][r];
            op[16] = acc[m][1][r];
            op[32] = acc[m][2][r];
            op[48] = acc[m][3][r];
        }
}

// ---------------------------------------------------------------- launch
extern "C" void kernel_launch(void* const* d_in, const int* in_sizes, int n_in,
                              void* d_out, int out_size, void* d_ws, size_t ws_size,
                              hipStream_t stream) {
    const float* in   = (const float*)d_in[0];
    const float* kofs = (const float*)d_in[1];
    const float* bias = (const float*)d_in[2];
    const float* filt = (const float*)d_in[3];
    float* out = (float*)d_out;
    float* ws  = (float*)d_ws;

    unsigned short* woffT = (unsigned short*)ws;
    unsigned short* filtT = (unsigned short*)(ws + FILTT_OFF_F);
    float*          wi32  = ws + WI32_OFF_F;

    hipLaunchKernelGGL(repack, dim3(1296), dim3(256), 0, stream, kofs, filt, woffT, filtT);
    hipLaunchKernelGGL(offset_conv_mfma, dim3(512), dim3(256), 0, stream, in, woffT, bias, wi32);
    hipLaunchKernelGGL(deform_wave, dim3(256), dim3(1024), 0, stream, in, filtT, wi32, out);
}